// Round 1
// baseline (112.895 us; speedup 1.0000x reference)
//
#include <hip/hip_runtime.h>

// PartitionPadding: scatter sorted atoms into zero-padded dense batch.
// Reformulated as a gather: out[m][p][:] = feat[starts[m]+p][:] if in range else 0.
//
// B=2048, MAX_ATOMS=640, D=64. Output = 2048*640*64 f32 = 335.5 MB.
// Input feat = N*64 f32 (N = in_sizes[0]/64, nominally 1e6). indicator int32 [N], sorted.

#define BATCH 2048
#define MAXA  640
#define DF    64

// starts[m] = lower_bound(ind, N, m) for m in [0, BATCH]; starts[BATCH] = N.
__global__ void pp_starts_kernel(const int* __restrict__ ind, int N,
                                 int* __restrict__ starts) {
    int m = blockIdx.x * blockDim.x + threadIdx.x;
    if (m > BATCH) return;
    if (m == BATCH) { starts[m] = N; return; }
    int lo = 0, hi = N;
    while (lo < hi) {
        int mid = (lo + hi) >> 1;
        if (ind[mid] < m) lo = mid + 1; else hi = mid;
    }
    starts[m] = lo;
}

// One float4 per thread. Row = 64 floats = 16 float4.
// grid = (MAXA*16/256 = 40, BATCH), block = 256.
__global__ void pp_gather_kernel(const float4* __restrict__ feat,
                                 const int* __restrict__ starts,
                                 float4* __restrict__ out) {
    const int m   = blockIdx.y;
    const int idx = blockIdx.x * blockDim.x + threadIdx.x;  // 0 .. MAXA*16-1
    const int p   = idx >> 4;   // row within molecule
    const int q   = idx & 15;   // float4 within row
    const int s   = starts[m];
    const int e   = starts[m + 1];
    float4 v = make_float4(0.f, 0.f, 0.f, 0.f);
    const int src = s + p;
    if (src < e) v = feat[(long long)src * 16 + q];
    out[((long long)m * MAXA + p) * 16 + q] = v;
}

extern "C" void kernel_launch(void* const* d_in, const int* in_sizes, int n_in,
                              void* d_out, int out_size, void* d_ws, size_t ws_size,
                              hipStream_t stream) {
    const float* feat = (const float*)d_in[0];
    const int*   ind  = (const int*)d_in[1];
    float*       out  = (float*)d_out;
    int*         starts = (int*)d_ws;   // BATCH+1 ints

    const int N = in_sizes[0] / DF;

    // 1) starts via per-molecule binary search (2049 threads, trivial cost)
    {
        dim3 grid((BATCH + 1 + 255) / 256);
        pp_starts_kernel<<<grid, 256, 0, stream>>>(ind, N, starts);
    }

    // 2) dense gather+pad: every output element written each call
    {
        dim3 grid(MAXA * (DF / 4) / 256, BATCH);  // (40, 2048)
        pp_gather_kernel<<<grid, 256, 0, stream>>>(
            (const float4*)feat, starts, (float4*)out);
    }
}